// Round 1
// baseline (1514.341 us; speedup 1.0000x reference)
//
#include <hip/hip_runtime.h>
#include <math.h>

#define B_ 2
#define D_ 256
#define N_ 8192
#define CI_ 128
#define M_ 4096
#define BN_EPS_ 1e-5f

// ---- workspace layout (float offsets) ----
#define OFF_WTG 0                          // g weights transposed   [256][128]
#define OFF_WTT (OFF_WTG + 32768)          // theta weights transposed
#define OFF_WTP (OFF_WTT + 32768)          // phi weights transposed
#define OFF_THT (OFF_WTP + 32768)          // theta_t [B][N][CI]   2,097,152
#define OFF_PHT (OFF_THT + 2097152)        // phi_t   [B][M][CI]   1,048,576
#define OFF_GT  (OFF_PHT + 1048576)        // g_t     [B][M][CI]   1,048,576
#define OFF_Y   (OFF_GT  + 1048576)        // y       [B][CI][N]   2,097,152
#define OFF_MEAN (OFF_Y + 2097152)
#define OFF_RSTD (OFF_MEAN + 256)

// ---------------- weight transpose: (CI,D) -> (D,CI) for g/theta/phi ----------------
__global__ __launch_bounds__(256) void transpose_w_kernel(
    const float* __restrict__ gw, const float* __restrict__ tw, const float* __restrict__ pw,
    float* __restrict__ wtg, float* __restrict__ wtt, float* __restrict__ wtp)
{
    int idx = blockIdx.x * 256 + threadIdx.x;      // 0 .. 98303
    int which = idx >> 15;                          // /32768
    int rem = idx & 32767;
    int d = rem >> 7;
    int c = rem & 127;
    const float* src = (which == 0) ? gw : (which == 1) ? tw : pw;
    float* dst = (which == 0) ? wtg : (which == 1) ? wtt : wtp;
    dst[rem] = src[c * D_ + d];
}

// ---------------- fused projections: theta_t, pooled g_t / phi_t ----------------
// grid (M/16, B), block 256. thread: c = tid&127, half = tid>>7, covers 16 n positions.
__global__ __launch_bounds__(256) void proj_kernel(
    const float* __restrict__ f,
    const float* __restrict__ wtt, const float* __restrict__ wtg, const float* __restrict__ wtp,
    const float* __restrict__ tb, const float* __restrict__ gb, const float* __restrict__ pb,
    float* __restrict__ th_t, float* __restrict__ g_t, float* __restrict__ ph_t)
{
    int tid = threadIdx.x;
    int c = tid & 127;
    int half = tid >> 7;
    int b = blockIdx.y;
    int n_base = blockIdx.x * 32 + half * 16;
    const float* fp = f + (size_t)b * D_ * N_ + n_base;

    float at[16], ag[16], ap[16];
#pragma unroll
    for (int j = 0; j < 16; j++) { at[j] = 0.f; ag[j] = 0.f; ap[j] = 0.f; }

#pragma unroll 4
    for (int d = 0; d < D_; d++) {
        float wt = wtt[d * CI_ + c];
        float wg = wtg[d * CI_ + c];
        float wp = wtp[d * CI_ + c];
        const float4* f4 = (const float4*)(fp + (size_t)d * N_);
#pragma unroll
        for (int k = 0; k < 4; k++) {
            float4 v = f4[k];
            at[4*k+0] = fmaf(wt, v.x, at[4*k+0]);
            at[4*k+1] = fmaf(wt, v.y, at[4*k+1]);
            at[4*k+2] = fmaf(wt, v.z, at[4*k+2]);
            at[4*k+3] = fmaf(wt, v.w, at[4*k+3]);
            ag[4*k+0] = fmaf(wg, v.x, ag[4*k+0]);
            ag[4*k+1] = fmaf(wg, v.y, ag[4*k+1]);
            ag[4*k+2] = fmaf(wg, v.z, ag[4*k+2]);
            ag[4*k+3] = fmaf(wg, v.w, ag[4*k+3]);
            ap[4*k+0] = fmaf(wp, v.x, ap[4*k+0]);
            ap[4*k+1] = fmaf(wp, v.y, ap[4*k+1]);
            ap[4*k+2] = fmaf(wp, v.z, ap[4*k+2]);
            ap[4*k+3] = fmaf(wp, v.w, ap[4*k+3]);
        }
    }

    float tbias = tb[c], gbias = gb[c], pbias = pb[c];
    float* tho = th_t + (size_t)b * N_ * CI_ + (size_t)n_base * CI_ + c;
#pragma unroll
    for (int j = 0; j < 16; j++) tho[(size_t)j * CI_] = at[j] + tbias;

    int m0 = blockIdx.x * 16 + half * 8;
    float* go = g_t + (size_t)b * M_ * CI_ + (size_t)m0 * CI_ + c;
    float* po = ph_t + (size_t)b * M_ * CI_ + (size_t)m0 * CI_ + c;
#pragma unroll
    for (int jj = 0; jj < 8; jj++) {
        go[(size_t)jj * CI_] = fmaxf(ag[2*jj], ag[2*jj+1]) + gbias;
        po[(size_t)jj * CI_] = fmaxf(ap[2*jj], ap[2*jj+1]) + pbias;
    }
}

// ---------------- flash attention (fp32) ----------------
// grid (N/32, B), block 128 (2 waves x 16 queries). KC=32 keys/chunk.
// lane: q = lane&15, sub = lane>>4 (key-group in S phase, channel-group in PV phase).
__global__ __launch_bounds__(128) void attn_kernel(
    const float* __restrict__ th_t, const float* __restrict__ ph_t,
    const float* __restrict__ g_t, float* __restrict__ y)
{
    __shared__ float sth[32 * 132];     // theta tile [q][c], pad 132
    __shared__ float sph[32 * 132];     // phi chunk (xor-swizzled) / g chunk (plain)
    __shared__ float sps[2 * 16 * 33];  // per-wave p tile [q][k], pad 33

    int tid = threadIdx.x;
    int wave = tid >> 6;
    int lane = tid & 63;
    int q = lane & 15;
    int sub = lane >> 4;
    int b = blockIdx.y;
    int q0 = blockIdx.x * 32;

    // stage theta tile: 32 rows x 128 floats = 1024 float4
    const float4* thg = (const float4*)(th_t + (size_t)b * N_ * CI_ + (size_t)q0 * CI_);
#pragma unroll
    for (int i = 0; i < 8; i++) {
        int idx = i * 128 + tid;
        int qq = idx >> 5, cb = idx & 31;
        float4 v = thg[idx];
        *((float4*)&sth[qq * 132 + cb * 4]) = v;
    }

    float m_i = -INFINITY, l_i = 0.f;
    float yacc[32];
#pragma unroll
    for (int j = 0; j < 32; j++) yacc[j] = 0.f;

    const float* myth = &sth[(wave * 16 + q) * 132];
    float* myp = &sps[(wave * 16 + q) * 33];
    const float4* phg = (const float4*)(ph_t + (size_t)b * M_ * CI_);
    const float4* gg  = (const float4*)(g_t  + (size_t)b * M_ * CI_);

    for (int kc = 0; kc < M_; kc += 32) {
        __syncthreads();   // previous PV reads of sph done (covers theta staging on iter 0)
        // stage phi chunk, 16B-block xor swizzle by (k>>3)
#pragma unroll
        for (int i = 0; i < 8; i++) {
            int idx = i * 128 + tid;
            int k = idx >> 5, cb = idx & 31;
            int cb2 = cb ^ ((k >> 3) & 3);
            float4 v = phg[(size_t)(kc + k) * 32 + cb];
            *((float4*)&sph[k * 132 + cb2 * 4]) = v;
        }
        __syncthreads();

        // S = theta . phi  (8 keys per lane, k = sub*8 + j)
        float s[8];
#pragma unroll
        for (int j = 0; j < 8; j++) s[j] = 0.f;
#pragma unroll 2
        for (int cb = 0; cb < 32; cb++) {
            float4 a = *((const float4*)&myth[cb * 4]);
            int cbx = cb ^ sub;
#pragma unroll
            for (int j = 0; j < 8; j++) {
                float4 p4 = *((const float4*)&sph[(sub * 8 + j) * 132 + cbx * 4]);
                s[j] = fmaf(a.x, p4.x, s[j]);
                s[j] = fmaf(a.y, p4.y, s[j]);
                s[j] = fmaf(a.z, p4.z, s[j]);
                s[j] = fmaf(a.w, p4.w, s[j]);
            }
        }

        // online softmax update (state replicated across the 4 sub-lanes of each q)
        float cmax = s[0];
#pragma unroll
        for (int j = 1; j < 8; j++) cmax = fmaxf(cmax, s[j]);
        cmax = fmaxf(cmax, __shfl_xor(cmax, 16, 64));
        cmax = fmaxf(cmax, __shfl_xor(cmax, 32, 64));
        float m_new = fmaxf(m_i, cmax);
        float alpha = __expf(m_i - m_new);
        float psum = 0.f;
#pragma unroll
        for (int j = 0; j < 8; j++) {
            float p = __expf(s[j] - m_new);
            myp[sub * 8 + j] = p;
            psum += p;
        }
        psum += __shfl_xor(psum, 16, 64);
        psum += __shfl_xor(psum, 32, 64);
        l_i = l_i * alpha + psum;
        m_i = m_new;

        __syncthreads();   // all waves done reading phi from sph
        // stage g chunk (plain layout)
#pragma unroll
        for (int i = 0; i < 8; i++) {
            int idx = i * 128 + tid;
            int k = idx >> 5, cb = idx & 31;
            float4 v = gg[(size_t)(kc + k) * 32 + cb];
            *((float4*)&sph[k * 132 + cb * 4]) = v;
        }
        __syncthreads();

        // PV: y[c] = y[c]*alpha + sum_k p[k] g[k][c]; lane owns c = ss*32 + sub*8 + j
#pragma unroll
        for (int j = 0; j < 32; j++) yacc[j] *= alpha;
#pragma unroll 2
        for (int k = 0; k < 32; k++) {
            float pk = sps[(wave * 16 + q) * 33 + k];
            const float* grow = &sph[k * 132 + sub * 8];
#pragma unroll
            for (int ss = 0; ss < 4; ss++) {
                float4 g0 = *((const float4*)&grow[ss * 32]);
                float4 g1 = *((const float4*)&grow[ss * 32 + 4]);
                yacc[ss*8+0] = fmaf(pk, g0.x, yacc[ss*8+0]);
                yacc[ss*8+1] = fmaf(pk, g0.y, yacc[ss*8+1]);
                yacc[ss*8+2] = fmaf(pk, g0.z, yacc[ss*8+2]);
                yacc[ss*8+3] = fmaf(pk, g0.w, yacc[ss*8+3]);
                yacc[ss*8+4] = fmaf(pk, g1.x, yacc[ss*8+4]);
                yacc[ss*8+5] = fmaf(pk, g1.y, yacc[ss*8+5]);
                yacc[ss*8+6] = fmaf(pk, g1.z, yacc[ss*8+6]);
                yacc[ss*8+7] = fmaf(pk, g1.w, yacc[ss*8+7]);
            }
        }
    }

    // write y[b][c][n]
    float inv_l = 1.0f / l_i;
    int qg = q0 + wave * 16 + q;
    float* yo = y + (size_t)b * CI_ * N_ + qg;
#pragma unroll
    for (int ss = 0; ss < 4; ss++) {
#pragma unroll
        for (int j = 0; j < 8; j++) {
            int cc = ss * 32 + sub * 8 + j;
            yo[(size_t)cc * N_] = yacc[ss * 8 + j] * inv_l;
        }
    }
}

// ---------------- Wy = W_w @ y + W_b  -> d_out (scratch) ----------------
// grid (N/256, D/8, B), block 256
__global__ __launch_bounds__(256) void wy_kernel(
    const float* __restrict__ y, const float* __restrict__ Ww,
    const float* __restrict__ Wb, float* __restrict__ out)
{
    int n = blockIdx.x * 256 + threadIdx.x;
    int d0 = blockIdx.y * 8;
    int b = blockIdx.z;
    const float* yp = y + (size_t)b * CI_ * N_ + n;
    float acc[8];
#pragma unroll
    for (int dd = 0; dd < 8; dd++) acc[dd] = 0.f;
#pragma unroll 4
    for (int c = 0; c < CI_; c++) {
        float yv = yp[(size_t)c * N_];
#pragma unroll
        for (int dd = 0; dd < 8; dd++)
            acc[dd] = fmaf(Ww[(d0 + dd) * CI_ + c], yv, acc[dd]);
    }
    float* op = out + (size_t)b * D_ * N_ + (size_t)d0 * N_ + n;
#pragma unroll
    for (int dd = 0; dd < 8; dd++) op[(size_t)dd * N_] = acc[dd] + Wb[d0 + dd];
}

// ---------------- per-channel batch stats over (b, n) ----------------
__global__ __launch_bounds__(256) void stats_kernel(
    const float* __restrict__ wy, float* __restrict__ mean, float* __restrict__ rstd)
{
    __shared__ float ssum[256], ssq[256];
    int d = blockIdx.x;
    int tid = threadIdx.x;
    float s = 0.f, sq = 0.f;
    for (int b = 0; b < B_; b++) {
        const float* p = wy + (size_t)b * D_ * N_ + (size_t)d * N_;
        for (int i = tid; i < N_; i += 256) {
            float v = p[i];
            s += v;
            sq = fmaf(v, v, sq);
        }
    }
    ssum[tid] = s; ssq[tid] = sq;
    __syncthreads();
    for (int st = 128; st > 0; st >>= 1) {
        if (tid < st) { ssum[tid] += ssum[tid + st]; ssq[tid] += ssq[tid + st]; }
        __syncthreads();
    }
    if (tid == 0) {
        float inv = 1.0f / (float)(B_ * N_);
        float mn = ssum[0] * inv;
        float var = ssq[0] * inv - mn * mn;
        mean[d] = mn;
        rstd[d] = rsqrtf(var + BN_EPS_);
    }
}

// ---------------- BN (affine) + residual, in-place on d_out ----------------
__global__ __launch_bounds__(256) void bn_res_kernel(
    float* __restrict__ out, const float* __restrict__ f,
    const float* __restrict__ mean, const float* __restrict__ rstd,
    const float* __restrict__ gamma, const float* __restrict__ beta)
{
    int i = blockIdx.x * 256 + threadIdx.x;        // float4 index
    size_t e = (size_t)i * 4;
    int d = (int)((e >> 13) & 255);                 // N = 2^13
    float4 wy = ((const float4*)out)[i];
    float4 ff = ((const float4*)f)[i];
    float sc = rstd[d] * gamma[d];
    float mn = mean[d];
    float bt = beta[d];
    float4 r;
    r.x = (wy.x - mn) * sc + bt + ff.x;
    r.y = (wy.y - mn) * sc + bt + ff.y;
    r.z = (wy.z - mn) * sc + bt + ff.z;
    r.w = (wy.w - mn) * sc + bt + ff.w;
    ((float4*)out)[i] = r;
}

extern "C" void kernel_launch(void* const* d_in, const int* in_sizes, int n_in,
                              void* d_out, int out_size, void* d_ws, size_t ws_size,
                              hipStream_t stream)
{
    const float* f   = (const float*)d_in[0];
    const float* g_w = (const float*)d_in[1];
    const float* g_b = (const float*)d_in[2];
    const float* t_w = (const float*)d_in[3];
    const float* t_b = (const float*)d_in[4];
    const float* p_w = (const float*)d_in[5];
    const float* p_b = (const float*)d_in[6];
    const float* W_w = (const float*)d_in[7];
    const float* W_b = (const float*)d_in[8];
    const float* gam = (const float*)d_in[9];
    const float* bet = (const float*)d_in[10];
    float* out = (float*)d_out;
    float* ws = (float*)d_ws;

    float* wtg  = ws + OFF_WTG;
    float* wtt  = ws + OFF_WTT;
    float* wtp  = ws + OFF_WTP;
    float* th_t = ws + OFF_THT;
    float* ph_t = ws + OFF_PHT;
    float* g_t  = ws + OFF_GT;
    float* yws  = ws + OFF_Y;
    float* mnp  = ws + OFF_MEAN;
    float* rsp  = ws + OFF_RSTD;

    transpose_w_kernel<<<384, 256, 0, stream>>>(g_w, t_w, p_w, wtg, wtt, wtp);
    proj_kernel<<<dim3(M_ / 16, B_), 256, 0, stream>>>(f, wtt, wtg, wtp, t_b, g_b, p_b,
                                                       th_t, g_t, ph_t);
    attn_kernel<<<dim3(N_ / 32, B_), 128, 0, stream>>>(th_t, ph_t, g_t, yws);
    wy_kernel<<<dim3(N_ / 256, D_ / 8, B_), 256, 0, stream>>>(yws, W_w, W_b, out);
    stats_kernel<<<D_, 256, 0, stream>>>(out, mnp, rsp);
    bn_res_kernel<<<(B_ * D_ * N_ / 4) / 256, 256, 0, stream>>>(out, f, mnp, rsp, gam, bet);
}

// Round 2
// 349.122 us; speedup vs baseline: 4.3376x; 4.3376x over previous
//
#include <hip/hip_runtime.h>
#include <hip/hip_bf16.h>
#include <math.h>

#define B_ 2
#define D_ 256
#define N_ 8192
#define CI_ 128
#define M_ 4096
#define BN_EPS_ 1e-5f

// ---- workspace layout (float offsets) ----
#define OFF_WTG 0                          // g weights transposed   [256][128] fp32
#define OFF_WTT (OFF_WTG + 32768)
#define OFF_WTP (OFF_WTT + 32768)
#define OFF_THT (OFF_WTP + 32768)          // theta bf16 [B][N][CI]  2,097,152 elems = 1,048,576 f
#define OFF_PHT (OFF_THT + 1048576)        // phi   bf16 [B][M][CI]  1,048,576 elems = 524,288 f
#define OFF_GT  (OFF_PHT + 524288)         // g     bf16 [B][CI][M]  1,048,576 elems = 524,288 f
#define OFF_YP  (OFF_GT  + 524288)         // y partial fp32 [2][B][CI][N] = 4,194,304 f
#define OFF_ML  (OFF_YP  + 4194304)        // m/l fp32 [2][B][2][N] = 65,536 f
#define OFF_Y   (OFF_ML  + 65536)          // y fp32 [B][CI][N] = 2,097,152 f
#define OFF_MEAN (OFF_Y + 2097152)
#define OFF_RSTD (OFF_MEAN + 256)

typedef __attribute__((ext_vector_type(8))) short bfrag;   // 8 bf16 = 4 VGPRs
typedef __attribute__((ext_vector_type(4))) float f4v;     // MFMA accumulator
typedef __attribute__((ext_vector_type(4))) short s4v;     // 4 bf16 (b64 store)

// ---------------- weight transpose: (CI,D) -> (D,CI) for g/theta/phi ----------------
__global__ __launch_bounds__(256) void transpose_w_kernel(
    const float* __restrict__ gw, const float* __restrict__ tw, const float* __restrict__ pw,
    float* __restrict__ wtg, float* __restrict__ wtt, float* __restrict__ wtp)
{
    int idx = blockIdx.x * 256 + threadIdx.x;      // 0 .. 98303
    int which = idx >> 15;
    int rem = idx & 32767;
    int d = rem >> 7;
    int c = rem & 127;
    const float* src = (which == 0) ? gw : (which == 1) ? tw : pw;
    float* dst = (which == 0) ? wtg : (which == 1) ? wtt : wtp;
    dst[rem] = src[c * D_ + d];
}

// ---------------- fused projections -> bf16: theta [B][N][CI], phi [B][M][CI], g [B][CI][M] ----
__global__ __launch_bounds__(256) void proj_kernel(
    const float* __restrict__ f,
    const float* __restrict__ wtt, const float* __restrict__ wtg, const float* __restrict__ wtp,
    const float* __restrict__ tb, const float* __restrict__ gb, const float* __restrict__ pb,
    __hip_bfloat16* __restrict__ th_t, __hip_bfloat16* __restrict__ g_t,
    __hip_bfloat16* __restrict__ ph_t)
{
    int tid = threadIdx.x;
    int c = tid & 127;
    int half = tid >> 7;
    int b = blockIdx.y;
    int n_base = blockIdx.x * 32 + half * 16;
    const float* fp = f + (size_t)b * D_ * N_ + n_base;

    float at[16], ag[16], ap[16];
#pragma unroll
    for (int j = 0; j < 16; j++) { at[j] = 0.f; ag[j] = 0.f; ap[j] = 0.f; }

#pragma unroll 4
    for (int d = 0; d < D_; d++) {
        float wt = wtt[d * CI_ + c];
        float wg = wtg[d * CI_ + c];
        float wp = wtp[d * CI_ + c];
        const float4* f4 = (const float4*)(fp + (size_t)d * N_);
#pragma unroll
        for (int k = 0; k < 4; k++) {
            float4 v = f4[k];
            at[4*k+0] = fmaf(wt, v.x, at[4*k+0]);
            at[4*k+1] = fmaf(wt, v.y, at[4*k+1]);
            at[4*k+2] = fmaf(wt, v.z, at[4*k+2]);
            at[4*k+3] = fmaf(wt, v.w, at[4*k+3]);
            ag[4*k+0] = fmaf(wg, v.x, ag[4*k+0]);
            ag[4*k+1] = fmaf(wg, v.y, ag[4*k+1]);
            ag[4*k+2] = fmaf(wg, v.z, ag[4*k+2]);
            ag[4*k+3] = fmaf(wg, v.w, ag[4*k+3]);
            ap[4*k+0] = fmaf(wp, v.x, ap[4*k+0]);
            ap[4*k+1] = fmaf(wp, v.y, ap[4*k+1]);
            ap[4*k+2] = fmaf(wp, v.z, ap[4*k+2]);
            ap[4*k+3] = fmaf(wp, v.w, ap[4*k+3]);
        }
    }

    float tbias = tb[c], gbias = gb[c], pbias = pb[c];
    __hip_bfloat16* tho = th_t + (size_t)b * N_ * CI_ + (size_t)n_base * CI_ + c;
#pragma unroll
    for (int j = 0; j < 16; j++) tho[(size_t)j * CI_] = __float2bfloat16(at[j] + tbias);

    int m0 = blockIdx.x * 16 + half * 8;
    __hip_bfloat16* go = g_t + ((size_t)b * CI_ + c) * M_ + m0;
    __hip_bfloat16* po = ph_t + (size_t)b * M_ * CI_ + (size_t)m0 * CI_ + c;
#pragma unroll
    for (int jj = 0; jj < 8; jj++) {
        go[jj] = __float2bfloat16(fmaxf(ag[2*jj], ag[2*jj+1]) + gbias);
        po[(size_t)jj * CI_] = __float2bfloat16(fmaxf(ap[2*jj], ap[2*jj+1]) + pbias);
    }
}

// ---------------- MFMA flash attention, bf16, key-split 2 ----------------
// block 256 = 4 waves, each wave owns 32 q (2 frags of 16). Q-tile 128, KC=64.
// grid (N/128, B, 2). Writes unnormalized y^T partials + (m,l).
__global__ __launch_bounds__(256, 1) void attn_kernel(
    const __hip_bfloat16* __restrict__ th_p, const __hip_bfloat16* __restrict__ ph_p,
    const __hip_bfloat16* __restrict__ g_p, float* __restrict__ yp, float* __restrict__ ml)
{
    __shared__ short sTh[128 * 136];   // theta [q][c], stride 272 B (17x16B)
    __shared__ short sPh[64 * 136];    // phi   [k][c]
    __shared__ short sG [128 * 72];    // g^T   [c][k], stride 144 B (9x16B)
    __shared__ short sP [4 * 32 * 72]; // per-wave P [q][k]

    const int tid = threadIdx.x;
    const int wave = tid >> 6, lane = tid & 63;
    const int lq = lane & 15, quad = lane >> 4;
    const int b = blockIdx.y, split = blockIdx.z;
    const int q0 = blockIdx.x * 128;

    // stage theta tile: 128 rows x 256 B
    const short* thg = (const short*)th_p + (size_t)b * N_ * CI_ + (size_t)q0 * CI_;
#pragma unroll
    for (int p = 0; p < 8; p++) {
        int idx = p * 256 + tid;
        int r = idx >> 4, u = idx & 15;
        *(float4*)&sTh[r * 136 + u * 8] = *(const float4*)&thg[r * 128 + u * 8];
    }

    f4v yacc[2][8];
#pragma unroll
    for (int qf = 0; qf < 2; qf++)
#pragma unroll
        for (int ct = 0; ct < 8; ct++) yacc[qf][ct] = (f4v){0.f, 0.f, 0.f, 0.f};
    float mI[2] = {-INFINITY, -INFINITY};
    float lI[2] = {0.f, 0.f};

    const short* phg = (const short*)ph_p + (size_t)b * M_ * CI_;
    const short* gg  = (const short*)g_p + (size_t)b * CI_ * M_;

    const int kend = split * 2048 + 2048;
    for (int kc = split * 2048; kc < kend; kc += 64) {
        __syncthreads();
        // stage phi chunk: 64 rows x 256 B
#pragma unroll
        for (int p = 0; p < 4; p++) {
            int idx = p * 256 + tid;
            int r = idx >> 4, u = idx & 15;
            *(float4*)&sPh[r * 136 + u * 8] = *(const float4*)&phg[(size_t)(kc + r) * 128 + u * 8];
        }
        // stage g^T chunk: 128 rows x 128 B
#pragma unroll
        for (int p = 0; p < 4; p++) {
            int idx = p * 256 + tid;
            int r = idx >> 3, u = idx & 7;
            *(float4*)&sG[r * 72 + u * 8] = *(const float4*)&gg[(size_t)r * M_ + kc + u * 8];
        }
        __syncthreads();

        // theta B-fragments (reused across all 4 key tiles)
        bfrag tf[2][4];
#pragma unroll
        for (int qf = 0; qf < 2; qf++)
#pragma unroll
            for (int cb = 0; cb < 4; cb++)
                tf[qf][cb] = *(const bfrag*)&sTh[(wave * 32 + qf * 16 + lq) * 136 + cb * 32 + quad * 8];

        // S^T = phi . theta : lane holds S[key = t*16+quad*4+r][q = lane&15]
        f4v sv[2][4];
#pragma unroll
        for (int t = 0; t < 4; t++) {
            f4v a0 = (f4v){0.f, 0.f, 0.f, 0.f};
            f4v a1 = (f4v){0.f, 0.f, 0.f, 0.f};
#pragma unroll
            for (int cb = 0; cb < 4; cb++) {
                bfrag pa = *(const bfrag*)&sPh[(t * 16 + lq) * 136 + cb * 32 + quad * 8];
                a0 = __builtin_amdgcn_mfma_f32_16x16x32_bf16(pa, tf[0][cb], a0, 0, 0, 0);
                a1 = __builtin_amdgcn_mfma_f32_16x16x32_bf16(pa, tf[1][cb], a1, 0, 0, 0);
            }
            sv[0][t] = a0; sv[1][t] = a1;
        }

        // online softmax per q (q = lane&15; reduce over regs, then quads)
        float alpha[2];
#pragma unroll
        for (int qf = 0; qf < 2; qf++) {
            float mx = sv[qf][0][0];
#pragma unroll
            for (int t = 0; t < 4; t++)
#pragma unroll
                for (int r = 0; r < 4; r++) mx = fmaxf(mx, sv[qf][t][r]);
            mx = fmaxf(mx, __shfl_xor(mx, 16));
            mx = fmaxf(mx, __shfl_xor(mx, 32));
            float mnew = fmaxf(mI[qf], mx);
            float al = __expf(mI[qf] - mnew);
            float ps = 0.f;
#pragma unroll
            for (int t = 0; t < 4; t++) {
                s4v pk;
#pragma unroll
                for (int r = 0; r < 4; r++) {
                    float pv = __expf(sv[qf][t][r] - mnew);
                    ps += pv;
                    unsigned uu = __float_as_uint(pv);
                    uu += 0x7fff + ((uu >> 16) & 1);   // RNE to bf16
                    pk[r] = (short)(uu >> 16);
                }
                *(s4v*)&sP[wave * 2304 + (qf * 16 + lq) * 72 + t * 16 + quad * 4] = pk;
            }
            ps += __shfl_xor(ps, 16);
            ps += __shfl_xor(ps, 32);
            lI[qf] = lI[qf] * al + ps;
            mI[qf] = mnew;
            alpha[qf] = al;
        }

        // P B-fragments (per-wave region; same-wave write->read, no barrier needed)
        bfrag pf[2][2];
#pragma unroll
        for (int qf = 0; qf < 2; qf++)
#pragma unroll
            for (int kh = 0; kh < 2; kh++)
                pf[qf][kh] = *(const bfrag*)&sP[wave * 2304 + (qf * 16 + lq) * 72 + kh * 32 + quad * 8];

        // rescale accumulators
#pragma unroll
        for (int qf = 0; qf < 2; qf++)
#pragma unroll
            for (int ct = 0; ct < 8; ct++) yacc[qf][ct] *= alpha[qf];

        // y^T += g^T . P : lane holds y[c = ct*16+quad*4+r][q = lane&15]
#pragma unroll
        for (int ct = 0; ct < 8; ct++)
#pragma unroll
            for (int kh = 0; kh < 2; kh++) {
                bfrag ga = *(const bfrag*)&sG[(ct * 16 + lq) * 72 + kh * 32 + quad * 8];
                yacc[0][ct] = __builtin_amdgcn_mfma_f32_16x16x32_bf16(ga, pf[0][kh], yacc[0][ct], 0, 0, 0);
                yacc[1][ct] = __builtin_amdgcn_mfma_f32_16x16x32_bf16(ga, pf[1][kh], yacc[1][ct], 0, 0, 0);
            }
    }

    // epilogue: unnormalized partials + (m,l)
    float* yb = yp + ((size_t)split * B_ + b) * CI_ * N_;
#pragma unroll
    for (int qf = 0; qf < 2; qf++) {
        int qg = q0 + wave * 32 + qf * 16 + lq;
#pragma unroll
        for (int ct = 0; ct < 8; ct++)
#pragma unroll
            for (int r = 0; r < 4; r++)
                yb[(size_t)(ct * 16 + quad * 4 + r) * N_ + qg] = yacc[qf][ct][r];
        if (quad == 0) {
            ml[((split * B_ + b) * 2 + 0) * N_ + qg] = mI[qf];
            ml[((split * B_ + b) * 2 + 1) * N_ + qg] = lI[qf];
        }
    }
}

// ---------------- flash merge of the two key-splits ----------------
__global__ __launch_bounds__(256) void merge_kernel(
    const float* __restrict__ yp, const float* __restrict__ ml, float* __restrict__ y)
{
    int idx = blockIdx.x * 256 + threadIdx.x;   // over CI*N/4
    int b = blockIdx.y;
    int e = idx * 4;
    int c = e >> 13;
    int n0 = e & (N_ - 1);
    const float* mlb0 = ml + ((0 * B_ + b) * 2) * N_;
    const float* mlb1 = ml + ((1 * B_ + b) * 2) * N_;
    const float* y0p = yp + (((size_t)0 * B_ + b) * CI_ + c) * N_;
    const float* y1p = yp + (((size_t)1 * B_ + b) * CI_ + c) * N_;
    float* yo = y + ((size_t)b * CI_ + c) * N_;
#pragma unroll
    for (int j = 0; j < 4; j++) {
        int n = n0 + j;
        float m0 = mlb0[n], l0 = mlb0[N_ + n];
        float m1 = mlb1[n], l1 = mlb1[N_ + n];
        float ms = fmaxf(m0, m1);
        float e0 = __expf(m0 - ms), e1 = __expf(m1 - ms);
        float den = 1.f / (l0 * e0 + l1 * e1);
        yo[n] = (y0p[n] * e0 + y1p[n] * e1) * den;
    }
}

// ---------------- Wy = W_w @ y + W_b  -> d_out (scratch) ----------------
// grid (N/256, D/32, B), block 256, 32 d-channels per thread
__global__ __launch_bounds__(256) void wy_kernel(
    const float* __restrict__ y, const float* __restrict__ Ww,
    const float* __restrict__ Wb, float* __restrict__ out)
{
    int n = blockIdx.x * 256 + threadIdx.x;
    int d0 = blockIdx.y * 32;
    int b = blockIdx.z;
    const float* ypb = y + (size_t)b * CI_ * N_ + n;
    float acc[32];
#pragma unroll
    for (int dd = 0; dd < 32; dd++) acc[dd] = 0.f;
#pragma unroll 4
    for (int c = 0; c < CI_; c++) {
        float yv = ypb[(size_t)c * N_];
#pragma unroll
        for (int dd = 0; dd < 32; dd++)
            acc[dd] = fmaf(Ww[(d0 + dd) * CI_ + c], yv, acc[dd]);
    }
    float* op = out + (size_t)b * D_ * N_ + (size_t)d0 * N_ + n;
#pragma unroll
    for (int dd = 0; dd < 32; dd++) op[(size_t)dd * N_] = acc[dd] + Wb[d0 + dd];
}

// ---------------- per-channel batch stats over (b, n) ----------------
__global__ __launch_bounds__(256) void stats_kernel(
    const float* __restrict__ wy, float* __restrict__ mean, float* __restrict__ rstd)
{
    __shared__ float ssum[256], ssq[256];
    int d = blockIdx.x;
    int tid = threadIdx.x;
    float s = 0.f, sq = 0.f;
    for (int b = 0; b < B_; b++) {
        const float* p = wy + (size_t)b * D_ * N_ + (size_t)d * N_;
        for (int i = tid; i < N_; i += 256) {
            float v = p[i];
            s += v;
            sq = fmaf(v, v, sq);
        }
    }
    ssum[tid] = s; ssq[tid] = sq;
    __syncthreads();
    for (int st = 128; st > 0; st >>= 1) {
        if (tid < st) { ssum[tid] += ssum[tid + st]; ssq[tid] += ssq[tid + st]; }
        __syncthreads();
    }
    if (tid == 0) {
        float inv = 1.0f / (float)(B_ * N_);
        float mn = ssum[0] * inv;
        float var = ssq[0] * inv - mn * mn;
        mean[d] = mn;
        rstd[d] = rsqrtf(var + BN_EPS_);
    }
}

// ---------------- BN (affine) + residual, in-place on d_out ----------------
__global__ __launch_bounds__(256) void bn_res_kernel(
    float* __restrict__ out, const float* __restrict__ f,
    const float* __restrict__ mean, const float* __restrict__ rstd,
    const float* __restrict__ gamma, const float* __restrict__ beta)
{
    int i = blockIdx.x * 256 + threadIdx.x;        // float4 index
    size_t e = (size_t)i * 4;
    int d = (int)((e >> 13) & 255);
    float4 wy = ((const float4*)out)[i];
    float4 ff = ((const float4*)f)[i];
    float sc = rstd[d] * gamma[d];
    float mn = mean[d];
    float bt = beta[d];
    float4 r;
    r.x = (wy.x - mn) * sc + bt + ff.x;
    r.y = (wy.y - mn) * sc + bt + ff.y;
    r.z = (wy.z - mn) * sc + bt + ff.z;
    r.w = (wy.w - mn) * sc + bt + ff.w;
    ((float4*)out)[i] = r;
}

extern "C" void kernel_launch(void* const* d_in, const int* in_sizes, int n_in,
                              void* d_out, int out_size, void* d_ws, size_t ws_size,
                              hipStream_t stream)
{
    const float* f   = (const float*)d_in[0];
    const float* g_w = (const float*)d_in[1];
    const float* g_b = (const float*)d_in[2];
    const float* t_w = (const float*)d_in[3];
    const float* t_b = (const float*)d_in[4];
    const float* p_w = (const float*)d_in[5];
    const float* p_b = (const float*)d_in[6];
    const float* W_w = (const float*)d_in[7];
    const float* W_b = (const float*)d_in[8];
    const float* gam = (const float*)d_in[9];
    const float* bet = (const float*)d_in[10];
    float* out = (float*)d_out;
    float* ws = (float*)d_ws;

    float* wtg = ws + OFF_WTG;
    float* wtt = ws + OFF_WTT;
    float* wtp = ws + OFF_WTP;
    __hip_bfloat16* th_t = (__hip_bfloat16*)(ws + OFF_THT);
    __hip_bfloat16* ph_t = (__hip_bfloat16*)(ws + OFF_PHT);
    __hip_bfloat16* g_t  = (__hip_bfloat16*)(ws + OFF_GT);
    float* yp  = ws + OFF_YP;
    float* mlp = ws + OFF_ML;
    float* yws = ws + OFF_Y;
    float* mnp = ws + OFF_MEAN;
    float* rsp = ws + OFF_RSTD;

    transpose_w_kernel<<<384, 256, 0, stream>>>(g_w, t_w, p_w, wtg, wtt, wtp);
    proj_kernel<<<dim3(M_ / 16, B_), 256, 0, stream>>>(f, wtt, wtg, wtp, t_b, g_b, p_b,
                                                       th_t, g_t, ph_t);
    attn_kernel<<<dim3(N_ / 128, B_, 2), 256, 0, stream>>>(th_t, ph_t, g_t, yp, mlp);
    merge_kernel<<<dim3(CI_ * N_ / 4 / 256, B_), 256, 0, stream>>>(yp, mlp, yws);
    wy_kernel<<<dim3(N_ / 256, D_ / 32, B_), 256, 0, stream>>>(yws, W_w, W_b, out);
    stats_kernel<<<D_, 256, 0, stream>>>(out, mnp, rsp);
    bn_res_kernel<<<(B_ * D_ * N_ / 4) / 256, 256, 0, stream>>>(out, f, mnp, rsp, gam, bet);
}

// Round 3
// 256.785 us; speedup vs baseline: 5.8973x; 1.3596x over previous
//
#include <hip/hip_runtime.h>
#include <hip/hip_bf16.h>
#include <math.h>

#define B_ 2
#define D_ 256
#define N_ 8192
#define CI_ 128
#define M_ 4096
#define BN_EPS_ 1e-5f

// ---- workspace layout (float offsets) ----
#define OFF_WALL 0                          // bf16 [384][256] packed g/theta/phi weights
#define OFF_THT  49152                      // theta bf16 [B][N][CI]
#define OFF_PHT  (OFF_THT + 1048576)        // phi   bf16 [B][M][CI]
#define OFF_GT   (OFF_PHT + 524288)         // g     bf16 [B][CI][M]
#define OFF_YP   (OFF_GT  + 524288)         // y partial fp32 [2][B][CI][N]
#define OFF_ML   (OFF_YP  + 4194304)        // m/l fp32 [2][B][2][N]
#define OFF_Y    (OFF_ML  + 65536)          // y fp32 [B][CI][N]
#define OFF_MEAN (OFF_Y + 2097152)
#define OFF_RSTD (OFF_MEAN + 256)

typedef __attribute__((ext_vector_type(8))) short bfrag;   // 8 bf16 = 4 VGPRs
typedef __attribute__((ext_vector_type(4))) float f4v;     // MFMA accumulator
typedef __attribute__((ext_vector_type(4))) short s4v;     // 4 bf16 (b64 store)

__device__ inline unsigned short bf16rne(float x) {
    unsigned u = __float_as_uint(x);
    u += 0x7fff + ((u >> 16) & 1);
    return (unsigned short)(u >> 16);
}

// ---------------- pack g/theta/phi weights into bf16 Wall[384][256] ----------------
__global__ __launch_bounds__(256) void wconv_kernel(
    const float* __restrict__ gw, const float* __restrict__ tw, const float* __restrict__ pw,
    short* __restrict__ wall)
{
    int idx = blockIdx.x * 256 + threadIdx.x;      // 0 .. 98303
    int which = idx >> 15;
    int rem = idx & 32767;
    const float* src = (which == 0) ? gw : (which == 1) ? tw : pw;
    wall[idx] = (short)bf16rne(src[rem]);
}

// ---------------- MFMA projections ----------------
// Out[cc][n] = sum_d Wall[cc][d] * f[b][d][n], cc in [0,384): g | theta | phi.
// block 256 = 4 waves; wave owns 96 cc (6 frags) x 32 n (2 frags). grid (N/32, B).
// A-frags straight from global (L2-hot Wall); f transposed to bf16 via LDS.
__global__ __launch_bounds__(256, 2) void proj_kernel(
    const float* __restrict__ f, const short* __restrict__ wall,
    const float* __restrict__ tb, const float* __restrict__ gb, const float* __restrict__ pb,
    short* __restrict__ th_t, short* __restrict__ g_t, short* __restrict__ ph_t)
{
    __shared__ short sF[32 * 72];   // f chunk transposed [n][k], stride 72 shorts

    const int tid = threadIdx.x;
    const int wave = tid >> 6, lane = tid & 63;
    const int lq = lane & 15, quad = lane >> 4;
    const int b = blockIdx.y;
    const int n0 = blockIdx.x * 32;

    const float* fb = f + (size_t)b * D_ * N_;

    f4v acc[6][2];
#pragma unroll
    for (int ct = 0; ct < 6; ct++)
#pragma unroll
        for (int nf = 0; nf < 2; nf++) acc[ct][nf] = (f4v){0.f, 0.f, 0.f, 0.f};

    const int sn = tid & 31;     // staging: n within tile
    const int sgrp = tid >> 5;   // staging: d' group of 8

    for (int kc = 0; kc < D_; kc += 64) {
        __syncthreads();
        // stage f chunk [64 k][32 n] -> sF[n][k] bf16 (paired writes)
#pragma unroll
        for (int jj = 0; jj < 4; jj++) {
            int dd = kc + sgrp * 8 + 2 * jj;
            float v0 = fb[(size_t)dd * N_ + n0 + sn];
            float v1 = fb[(size_t)(dd + 1) * N_ + n0 + sn];
            unsigned pk = (unsigned)bf16rne(v0) | ((unsigned)bf16rne(v1) << 16);
            *(unsigned*)&sF[sn * 72 + sgrp * 8 + 2 * jj] = pk;
        }
        __syncthreads();

        bfrag afr[6][2], bfr[2][2];
#pragma unroll
        for (int ks = 0; ks < 2; ks++) {
#pragma unroll
            for (int nf = 0; nf < 2; nf++)
                bfr[nf][ks] = *(const bfrag*)&sF[(nf * 16 + lq) * 72 + ks * 32 + quad * 8];
#pragma unroll
            for (int ct = 0; ct < 6; ct++)
                afr[ct][ks] = *(const bfrag*)&wall[(wave * 96 + ct * 16 + lq) * 256 + kc + ks * 32 + quad * 8];
        }
#pragma unroll
        for (int ks = 0; ks < 2; ks++)
#pragma unroll
            for (int ct = 0; ct < 6; ct++) {
                acc[ct][0] = __builtin_amdgcn_mfma_f32_16x16x32_bf16(afr[ct][ks], bfr[0][ks], acc[ct][0], 0, 0, 0);
                acc[ct][1] = __builtin_amdgcn_mfma_f32_16x16x32_bf16(afr[ct][ks], bfr[1][ks], acc[ct][1], 0, 0, 0);
            }
    }

    // epilogue: cc row = wave*96 + ct*16 + quad*4 + r, col n = n0 + nf*16 + lq
#pragma unroll
    for (int ct = 0; ct < 6; ct++) {
        const int cf = wave * 6 + ct;
#pragma unroll
        for (int nf = 0; nf < 2; nf++) {
            f4v v = acc[ct][nf];
            const int n = n0 + nf * 16 + lq;
            if (cf < 8) {                 // g -> pooled, transposed [c][m]
                const int cb = cf * 16 + quad * 4;
                float pl[4];
#pragma unroll
                for (int r = 0; r < 4; r++) {
                    float o = __shfl_xor(v[r], 1);
                    pl[r] = fmaxf(v[r], o) + gb[cb + r];
                }
                if (!(lq & 1)) {
                    const int m = n >> 1;
#pragma unroll
                    for (int r = 0; r < 4; r++)
                        g_t[((size_t)b * CI_ + cb + r) * M_ + m] = (short)bf16rne(pl[r]);
                }
            } else if (cf < 16) {         // theta [n][c]
                const int cb = (cf - 8) * 16 + quad * 4;
                s4v o;
#pragma unroll
                for (int r = 0; r < 4; r++) o[r] = (short)bf16rne(v[r] + tb[cb + r]);
                *(s4v*)&th_t[((size_t)b * N_ + n) * CI_ + cb] = o;
            } else {                      // phi -> pooled [m][c]
                const int cb = (cf - 16) * 16 + quad * 4;
                float pl[4];
#pragma unroll
                for (int r = 0; r < 4; r++) {
                    float o = __shfl_xor(v[r], 1);
                    pl[r] = fmaxf(v[r], o) + pb[cb + r];
                }
                if (!(lq & 1)) {
                    const int m = n >> 1;
                    s4v o;
#pragma unroll
                    for (int r = 0; r < 4; r++) o[r] = (short)bf16rne(pl[r]);
                    *(s4v*)&ph_t[((size_t)b * M_ + m) * CI_ + cb] = o;
                }
            }
        }
    }
}

// ---------------- MFMA flash attention, bf16, key-split 2 ----------------
// block 256 = 4 waves, each wave owns 32 q (2 frags of 16). Q-tile 128, KC=64.
// grid (N/128, B, 2). Writes unnormalized y^T partials + (m,l).
__global__ __launch_bounds__(256, 1) void attn_kernel(
    const short* __restrict__ th_p, const short* __restrict__ ph_p,
    const short* __restrict__ g_p, float* __restrict__ yp, float* __restrict__ ml)
{
    __shared__ short sTh[128 * 136];   // theta [q][c], stride 272 B
    __shared__ short sPh[64 * 136];    // phi   [k][c]
    __shared__ short sG [128 * 72];    // g^T   [c][k], stride 144 B
    __shared__ short sP [4 * 32 * 72]; // per-wave P [q][k]

    const int tid = threadIdx.x;
    const int wave = tid >> 6, lane = tid & 63;
    const int lq = lane & 15, quad = lane >> 4;
    const int b = blockIdx.y, split = blockIdx.z;
    const int q0 = blockIdx.x * 128;

    const short* thg = th_p + (size_t)b * N_ * CI_ + (size_t)q0 * CI_;
#pragma unroll
    for (int p = 0; p < 8; p++) {
        int idx = p * 256 + tid;
        int r = idx >> 4, u = idx & 15;
        *(float4*)&sTh[r * 136 + u * 8] = *(const float4*)&thg[r * 128 + u * 8];
    }

    f4v yacc[2][8];
#pragma unroll
    for (int qf = 0; qf < 2; qf++)
#pragma unroll
        for (int ct = 0; ct < 8; ct++) yacc[qf][ct] = (f4v){0.f, 0.f, 0.f, 0.f};
    float mI[2] = {-INFINITY, -INFINITY};
    float lI[2] = {0.f, 0.f};

    const short* phg = ph_p + (size_t)b * M_ * CI_;
    const short* gg  = g_p + (size_t)b * CI_ * M_;

    const int kend = split * 2048 + 2048;
    for (int kc = split * 2048; kc < kend; kc += 64) {
        __syncthreads();
#pragma unroll
        for (int p = 0; p < 4; p++) {
            int idx = p * 256 + tid;
            int r = idx >> 4, u = idx & 15;
            *(float4*)&sPh[r * 136 + u * 8] = *(const float4*)&phg[(size_t)(kc + r) * 128 + u * 8];
        }
#pragma unroll
        for (int p = 0; p < 4; p++) {
            int idx = p * 256 + tid;
            int r = idx >> 3, u = idx & 7;
            *(float4*)&sG[r * 72 + u * 8] = *(const float4*)&gg[(size_t)r * M_ + kc + u * 8];
        }
        __syncthreads();

        bfrag tf[2][4];
#pragma unroll
        for (int qf = 0; qf < 2; qf++)
#pragma unroll
            for (int cb = 0; cb < 4; cb++)
                tf[qf][cb] = *(const bfrag*)&sTh[(wave * 32 + qf * 16 + lq) * 136 + cb * 32 + quad * 8];

        f4v sv[2][4];
#pragma unroll
        for (int t = 0; t < 4; t++) {
            f4v a0 = (f4v){0.f, 0.f, 0.f, 0.f};
            f4v a1 = (f4v){0.f, 0.f, 0.f, 0.f};
#pragma unroll
            for (int cb = 0; cb < 4; cb++) {
                bfrag pa = *(const bfrag*)&sPh[(t * 16 + lq) * 136 + cb * 32 + quad * 8];
                a0 = __builtin_amdgcn_mfma_f32_16x16x32_bf16(pa, tf[0][cb], a0, 0, 0, 0);
                a1 = __builtin_amdgcn_mfma_f32_16x16x32_bf16(pa, tf[1][cb], a1, 0, 0, 0);
            }
            sv[0][t] = a0; sv[1][t] = a1;
        }

        float alpha[2];
#pragma unroll
        for (int qf = 0; qf < 2; qf++) {
            float mx = sv[qf][0][0];
#pragma unroll
            for (int t = 0; t < 4; t++)
#pragma unroll
                for (int r = 0; r < 4; r++) mx = fmaxf(mx, sv[qf][t][r]);
            mx = fmaxf(mx, __shfl_xor(mx, 16));
            mx = fmaxf(mx, __shfl_xor(mx, 32));
            float mnew = fmaxf(mI[qf], mx);
            float al = __expf(mI[qf] - mnew);
            float ps = 0.f;
#pragma unroll
            for (int t = 0; t < 4; t++) {
                s4v pk;
#pragma unroll
                for (int r = 0; r < 4; r++) {
                    float pv = __expf(sv[qf][t][r] - mnew);
                    ps += pv;
                    pk[r] = (short)bf16rne(pv);
                }
                *(s4v*)&sP[wave * 2304 + (qf * 16 + lq) * 72 + t * 16 + quad * 4] = pk;
            }
            ps += __shfl_xor(ps, 16);
            ps += __shfl_xor(ps, 32);
            lI[qf] = lI[qf] * al + ps;
            mI[qf] = mnew;
            alpha[qf] = al;
        }

        bfrag pf[2][2];
#pragma unroll
        for (int qf = 0; qf < 2; qf++)
#pragma unroll
            for (int kh = 0; kh < 2; kh++)
                pf[qf][kh] = *(const bfrag*)&sP[wave * 2304 + (qf * 16 + lq) * 72 + kh * 32 + quad * 8];

#pragma unroll
        for (int qf = 0; qf < 2; qf++)
#pragma unroll
            for (int ct = 0; ct < 8; ct++) yacc[qf][ct] *= alpha[qf];

#pragma unroll
        for (int ct = 0; ct < 8; ct++)
#pragma unroll
            for (int kh = 0; kh < 2; kh++) {
                bfrag ga = *(const bfrag*)&sG[(ct * 16 + lq) * 72 + kh * 32 + quad * 8];
                yacc[0][ct] = __builtin_amdgcn_mfma_f32_16x16x32_bf16(ga, pf[0][kh], yacc[0][ct], 0, 0, 0);
                yacc[1][ct] = __builtin_amdgcn_mfma_f32_16x16x32_bf16(ga, pf[1][kh], yacc[1][ct], 0, 0, 0);
            }
    }

    float* yb = yp + ((size_t)split * B_ + b) * CI_ * N_;
#pragma unroll
    for (int qf = 0; qf < 2; qf++) {
        int qg = q0 + wave * 32 + qf * 16 + lq;
#pragma unroll
        for (int ct = 0; ct < 8; ct++)
#pragma unroll
            for (int r = 0; r < 4; r++)
                yb[(size_t)(ct * 16 + quad * 4 + r) * N_ + qg] = yacc[qf][ct][r];
        if (quad == 0) {
            ml[((split * B_ + b) * 2 + 0) * N_ + qg] = mI[qf];
            ml[((split * B_ + b) * 2 + 1) * N_ + qg] = lI[qf];
        }
    }
}

// ---------------- flash merge of the two key-splits ----------------
__global__ __launch_bounds__(256) void merge_kernel(
    const float* __restrict__ yp, const float* __restrict__ ml, float* __restrict__ y)
{
    int idx = blockIdx.x * 256 + threadIdx.x;
    int b = blockIdx.y;
    int e = idx * 4;
    int c = e >> 13;
    int n0 = e & (N_ - 1);
    const float* mlb0 = ml + ((0 * B_ + b) * 2) * N_;
    const float* mlb1 = ml + ((1 * B_ + b) * 2) * N_;
    const float* y0p = yp + (((size_t)0 * B_ + b) * CI_ + c) * N_;
    const float* y1p = yp + (((size_t)1 * B_ + b) * CI_ + c) * N_;
    float* yo = y + ((size_t)b * CI_ + c) * N_;
#pragma unroll
    for (int j = 0; j < 4; j++) {
        int n = n0 + j;
        float m0 = mlb0[n], l0 = mlb0[N_ + n];
        float m1 = mlb1[n], l1 = mlb1[N_ + n];
        float ms = fmaxf(m0, m1);
        float e0 = __expf(m0 - ms), e1 = __expf(m1 - ms);
        float den = 1.f / (l0 * e0 + l1 * e1);
        yo[n] = (y0p[n] * e0 + y1p[n] * e1) * den;
    }
}

// ---------------- Wy = W_w @ y + W_b  -> d_out (scratch) ----------------
__global__ __launch_bounds__(256) void wy_kernel(
    const float* __restrict__ y, const float* __restrict__ Ww,
    const float* __restrict__ Wb, float* __restrict__ out)
{
    int n = blockIdx.x * 256 + threadIdx.x;
    int d0 = blockIdx.y * 32;
    int b = blockIdx.z;
    const float* ypb = y + (size_t)b * CI_ * N_ + n;
    float acc[32];
#pragma unroll
    for (int dd = 0; dd < 32; dd++) acc[dd] = 0.f;
#pragma unroll 4
    for (int c = 0; c < CI_; c++) {
        float yv = ypb[(size_t)c * N_];
#pragma unroll
        for (int dd = 0; dd < 32; dd++)
            acc[dd] = fmaf(Ww[(d0 + dd) * CI_ + c], yv, acc[dd]);
    }
    float* op = out + (size_t)b * D_ * N_ + (size_t)d0 * N_ + n;
#pragma unroll
    for (int dd = 0; dd < 32; dd++) op[(size_t)dd * N_] = acc[dd] + Wb[d0 + dd];
}

// ---------------- per-channel batch stats over (b, n) ----------------
__global__ __launch_bounds__(256) void stats_kernel(
    const float* __restrict__ wy, float* __restrict__ mean, float* __restrict__ rstd)
{
    __shared__ float ssum[256], ssq[256];
    int d = blockIdx.x;
    int tid = threadIdx.x;
    float s = 0.f, sq = 0.f;
    for (int b = 0; b < B_; b++) {
        const float* p = wy + (size_t)b * D_ * N_ + (size_t)d * N_;
        for (int i = tid; i < N_; i += 256) {
            float v = p[i];
            s += v;
            sq = fmaf(v, v, sq);
        }
    }
    ssum[tid] = s; ssq[tid] = sq;
    __syncthreads();
    for (int st = 128; st > 0; st >>= 1) {
        if (tid < st) { ssum[tid] += ssum[tid + st]; ssq[tid] += ssq[tid + st]; }
        __syncthreads();
    }
    if (tid == 0) {
        float inv = 1.0f / (float)(B_ * N_);
        float mn = ssum[0] * inv;
        float var = ssq[0] * inv - mn * mn;
        mean[d] = mn;
        rstd[d] = rsqrtf(var + BN_EPS_);
    }
}

// ---------------- BN (affine) + residual, in-place on d_out ----------------
__global__ __launch_bounds__(256) void bn_res_kernel(
    float* __restrict__ out, const float* __restrict__ f,
    const float* __restrict__ mean, const float* __restrict__ rstd,
    const float* __restrict__ gamma, const float* __restrict__ beta)
{
    int i = blockIdx.x * 256 + threadIdx.x;
    size_t e = (size_t)i * 4;
    int d = (int)((e >> 13) & 255);
    float4 wy = ((const float4*)out)[i];
    float4 ff = ((const float4*)f)[i];
    float sc = rstd[d] * gamma[d];
    float mn = mean[d];
    float bt = beta[d];
    float4 r;
    r.x = (wy.x - mn) * sc + bt + ff.x;
    r.y = (wy.y - mn) * sc + bt + ff.y;
    r.z = (wy.z - mn) * sc + bt + ff.z;
    r.w = (wy.w - mn) * sc + bt + ff.w;
    ((float4*)out)[i] = r;
}

extern "C" void kernel_launch(void* const* d_in, const int* in_sizes, int n_in,
                              void* d_out, int out_size, void* d_ws, size_t ws_size,
                              hipStream_t stream)
{
    const float* f   = (const float*)d_in[0];
    const float* g_w = (const float*)d_in[1];
    const float* g_b = (const float*)d_in[2];
    const float* t_w = (const float*)d_in[3];
    const float* t_b = (const float*)d_in[4];
    const float* p_w = (const float*)d_in[5];
    const float* p_b = (const float*)d_in[6];
    const float* W_w = (const float*)d_in[7];
    const float* W_b = (const float*)d_in[8];
    const float* gam = (const float*)d_in[9];
    const float* bet = (const float*)d_in[10];
    float* out = (float*)d_out;
    float* ws = (float*)d_ws;

    short* wall = (short*)(ws + OFF_WALL);
    short* th_t = (short*)(ws + OFF_THT);
    short* ph_t = (short*)(ws + OFF_PHT);
    short* g_t  = (short*)(ws + OFF_GT);
    float* yp  = ws + OFF_YP;
    float* mlp = ws + OFF_ML;
    float* yws = ws + OFF_Y;
    float* mnp = ws + OFF_MEAN;
    float* rsp = ws + OFF_RSTD;

    wconv_kernel<<<384, 256, 0, stream>>>(g_w, t_w, p_w, wall);
    proj_kernel<<<dim3(N_ / 32, B_), 256, 0, stream>>>(f, wall, t_b, g_b, p_b,
                                                       th_t, g_t, ph_t);
    attn_kernel<<<dim3(N_ / 128, B_, 2), 256, 0, stream>>>(th_t, ph_t, g_t, yp, mlp);
    merge_kernel<<<dim3(CI_ * N_ / 4 / 256, B_), 256, 0, stream>>>(yp, mlp, yws);
    wy_kernel<<<dim3(N_ / 256, D_ / 32, B_), 256, 0, stream>>>(yws, W_w, W_b, out);
    stats_kernel<<<D_, 256, 0, stream>>>(out, mnp, rsp);
    bn_res_kernel<<<(B_ * D_ * N_ / 4) / 256, 256, 0, stream>>>(out, f, mnp, rsp, gam, bet);
}

// Round 4
// 224.928 us; speedup vs baseline: 6.7326x; 1.1416x over previous
//
#include <hip/hip_runtime.h>
#include <hip/hip_bf16.h>
#include <math.h>

#define B_ 2
#define D_ 256
#define N_ 8192
#define CI_ 128
#define M_ 4096
#define BN_EPS_ 1e-5f

// ---- workspace layout (float offsets) ----
#define OFF_WALL 0                          // bf16 [384][256] packed g/theta/phi weights
#define OFF_THT  49152                      // theta bf16 [B][N][CI]
#define OFF_PHT  (OFF_THT + 1048576)        // phi   bf16 [B][M][CI]
#define OFF_GT   (OFF_PHT + 524288)         // g     bf16 [B][CI][M]
#define OFF_YP   (OFF_GT  + 524288)         // y partial bf16 [4][B][CI][N] (4,194,304 float slots)
#define OFF_ML   (OFF_YP  + 4194304)        // m/l fp32 [4][B][2][N] = 131072 f
#define OFF_Y    (OFF_ML  + 131072)         // y fp32 [B][CI][N]
#define OFF_MEAN (OFF_Y + 2097152)
#define OFF_RSTD (OFF_MEAN + 256)

typedef __attribute__((ext_vector_type(8))) short bfrag;    // 8 bf16 = 4 VGPRs
typedef __attribute__((ext_vector_type(4))) float f4v;      // 16x16 accumulator
typedef __attribute__((ext_vector_type(16))) float f16v;    // 32x32 accumulator
typedef __attribute__((ext_vector_type(4))) short s4v;      // 4 bf16

__device__ inline unsigned short bf16rne(float x) {
    unsigned u = __float_as_uint(x);
    u += 0x7fff + ((u >> 16) & 1);
    return (unsigned short)(u >> 16);
}

// ---------------- pack g/theta/phi weights into bf16 Wall[384][256] ----------------
__global__ __launch_bounds__(256) void wconv_kernel(
    const float* __restrict__ gw, const float* __restrict__ tw, const float* __restrict__ pw,
    short* __restrict__ wall)
{
    int idx = blockIdx.x * 256 + threadIdx.x;      // 0 .. 98303
    int which = idx >> 15;
    int rem = idx & 32767;
    const float* src = (which == 0) ? gw : (which == 1) ? tw : pw;
    wall[idx] = (short)bf16rne(src[rem]);
}

// ---------------- MFMA projections ----------------
// Out[cc][n] = sum_d Wall[cc][d] * f[b][d][n], cc in [0,384): g | theta | phi.
// block 256 = 4 waves; wave owns 96 cc (6 frags) x 32 n (2 frags). grid (N/32, B).
__global__ __launch_bounds__(256, 2) void proj_kernel(
    const float* __restrict__ f, const short* __restrict__ wall,
    const float* __restrict__ tb, const float* __restrict__ gb, const float* __restrict__ pb,
    short* __restrict__ th_t, short* __restrict__ g_t, short* __restrict__ ph_t)
{
    __shared__ short sF[32 * 72];   // f chunk transposed [n][k], stride 72 shorts

    const int tid = threadIdx.x;
    const int wave = tid >> 6, lane = tid & 63;
    const int lq = lane & 15, quad = lane >> 4;
    const int b = blockIdx.y;
    const int n0 = blockIdx.x * 32;

    const float* fb = f + (size_t)b * D_ * N_;

    f4v acc[6][2];
#pragma unroll
    for (int ct = 0; ct < 6; ct++)
#pragma unroll
        for (int nf = 0; nf < 2; nf++) acc[ct][nf] = (f4v){0.f, 0.f, 0.f, 0.f};

    const int sn = tid & 31;     // staging: n within tile
    const int sgrp = tid >> 5;   // staging: d' group of 8

    for (int kc = 0; kc < D_; kc += 64) {
        __syncthreads();
#pragma unroll
        for (int jj = 0; jj < 4; jj++) {
            int dd = kc + sgrp * 8 + 2 * jj;
            float v0 = fb[(size_t)dd * N_ + n0 + sn];
            float v1 = fb[(size_t)(dd + 1) * N_ + n0 + sn];
            unsigned pk = (unsigned)bf16rne(v0) | ((unsigned)bf16rne(v1) << 16);
            *(unsigned*)&sF[sn * 72 + sgrp * 8 + 2 * jj] = pk;
        }
        __syncthreads();

        bfrag afr[6][2], bfr[2][2];
#pragma unroll
        for (int ks = 0; ks < 2; ks++) {
#pragma unroll
            for (int nf = 0; nf < 2; nf++)
                bfr[nf][ks] = *(const bfrag*)&sF[(nf * 16 + lq) * 72 + ks * 32 + quad * 8];
#pragma unroll
            for (int ct = 0; ct < 6; ct++)
                afr[ct][ks] = *(const bfrag*)&wall[(wave * 96 + ct * 16 + lq) * 256 + kc + ks * 32 + quad * 8];
        }
#pragma unroll
        for (int ks = 0; ks < 2; ks++)
#pragma unroll
            for (int ct = 0; ct < 6; ct++) {
                acc[ct][0] = __builtin_amdgcn_mfma_f32_16x16x32_bf16(afr[ct][ks], bfr[0][ks], acc[ct][0], 0, 0, 0);
                acc[ct][1] = __builtin_amdgcn_mfma_f32_16x16x32_bf16(afr[ct][ks], bfr[1][ks], acc[ct][1], 0, 0, 0);
            }
    }

#pragma unroll
    for (int ct = 0; ct < 6; ct++) {
        const int cf = wave * 6 + ct;
#pragma unroll
        for (int nf = 0; nf < 2; nf++) {
            f4v v = acc[ct][nf];
            const int n = n0 + nf * 16 + lq;
            if (cf < 8) {                 // g -> pooled, transposed [c][m]
                const int cb = cf * 16 + quad * 4;
                float pl[4];
#pragma unroll
                for (int r = 0; r < 4; r++) {
                    float o = __shfl_xor(v[r], 1);
                    pl[r] = fmaxf(v[r], o) + gb[cb + r];
                }
                if (!(lq & 1)) {
                    const int m = n >> 1;
#pragma unroll
                    for (int r = 0; r < 4; r++)
                        g_t[((size_t)b * CI_ + cb + r) * M_ + m] = (short)bf16rne(pl[r]);
                }
            } else if (cf < 16) {         // theta [n][c]
                const int cb = (cf - 8) * 16 + quad * 4;
                s4v o;
#pragma unroll
                for (int r = 0; r < 4; r++) o[r] = (short)bf16rne(v[r] + tb[cb + r]);
                *(s4v*)&th_t[((size_t)b * N_ + n) * CI_ + cb] = o;
            } else {                      // phi -> pooled [m][c]
                const int cb = (cf - 16) * 16 + quad * 4;
                float pl[4];
#pragma unroll
                for (int r = 0; r < 4; r++) {
                    float o = __shfl_xor(v[r], 1);
                    pl[r] = fmaxf(v[r], o) + pb[cb + r];
                }
                if (!(lq & 1)) {
                    const int m = n >> 1;
                    s4v o;
#pragma unroll
                    for (int r = 0; r < 4; r++) o[r] = (short)bf16rne(pl[r]);
                    *(s4v*)&ph_t[((size_t)b * M_ + m) * CI_ + cb] = o;
                }
            }
        }
    }
}

// ---------------- MFMA flash attention, 32x32 tiles, key-split 4 ----------------
// block 256 = 4 waves; wave owns 32 q. Q-tile 128, KC=64 keys/chunk, 16 chunks.
// theta B-frags live in registers; S^T = phi.theta; PV: y^T = g^T.P.
// grid (N/128, B, 4). Writes bf16 unnormalized y^T partials + fp32 (m,l).
__global__ __launch_bounds__(256, 2) void attn_kernel(
    const short* __restrict__ th_p, const short* __restrict__ ph_p,
    const short* __restrict__ g_p, short* __restrict__ yp, float* __restrict__ ml)
{
    __shared__ short sPh[64 * 136];    // phi  [key][ci], 272 B rows (17x16B, odd)
    __shared__ short sG [128 * 72];    // g^T  [c][key],  144 B rows (9x16B, odd)
    __shared__ short sP [4 * 32 * 88]; // per-wave P [q][key], 176 B rows (11x16B, odd)

    const int tid = threadIdx.x;
    const int wave = tid >> 6, lane = tid & 63;
    const int l = lane & 31, h = lane >> 5;
    const int b = blockIdx.y, split = blockIdx.z;
    const int q0 = blockIdx.x * 128;
    const int qg = q0 + wave * 32 + l;

    // theta B-fragments in registers: B[k = 16s + 8h + j][n = q]
    const short* thr = th_p + ((size_t)b * N_ + qg) * CI_;
    bfrag tf[8];
#pragma unroll
    for (int s = 0; s < 8; s++)
        tf[s] = *(const bfrag*)&thr[s * 16 + h * 8];

    f16v yacc[4];
#pragma unroll
    for (int ct = 0; ct < 4; ct++)
#pragma unroll
        for (int r = 0; r < 16; r++) yacc[ct][r] = 0.f;
    float mI = -INFINITY, lI = 0.f;

    const short* phg = ph_p + (size_t)b * M_ * CI_;
    const short* gg  = g_p + (size_t)b * CI_ * M_;
    short* sPw = &sP[wave * (32 * 88)];

    const int k0 = split * 1024;
    for (int kc = k0; kc < k0 + 1024; kc += 64) {
        __syncthreads();
        // stage phi chunk: 64 rows x 256 B
#pragma unroll
        for (int p = 0; p < 4; p++) {
            int idx = p * 256 + tid;
            int r = idx >> 4, u = idx & 15;
            *(float4*)&sPh[r * 136 + u * 8] = *(const float4*)&phg[(size_t)(kc + r) * 128 + u * 8];
        }
        // stage g^T chunk: 128 rows x 128 B
#pragma unroll
        for (int p = 0; p < 4; p++) {
            int idx = p * 256 + tid;
            int r = idx >> 3, u = idx & 7;
            *(float4*)&sG[r * 72 + u * 8] = *(const float4*)&gg[(size_t)r * M_ + kc + u * 8];
        }
        __syncthreads();

        // S^T = phi . theta : 2 key-tiles of 32; lane holds col q = l, 16 key-rows/tile
        f16v sv[2];
#pragma unroll
        for (int kt = 0; kt < 2; kt++) {
            f16v a;
#pragma unroll
            for (int r = 0; r < 16; r++) a[r] = 0.f;
#pragma unroll
            for (int s = 0; s < 8; s++) {
                bfrag pa = *(const bfrag*)&sPh[(kt * 32 + l) * 136 + s * 16 + h * 8];
                a = __builtin_amdgcn_mfma_f32_32x32x16_bf16(pa, tf[s], a, 0, 0, 0);
            }
            sv[kt] = a;
        }

        // online softmax for q = l (keys split across h halves: one shfl)
        float mx = sv[0][0];
#pragma unroll
        for (int kt = 0; kt < 2; kt++)
#pragma unroll
            for (int r = 0; r < 16; r++) mx = fmaxf(mx, sv[kt][r]);
        mx = fmaxf(mx, __shfl_xor(mx, 32));
        float mnew = fmaxf(mI, mx);
        float al = __expf(mI - mnew);
        float ps = 0.f;
#pragma unroll
        for (int kt = 0; kt < 2; kt++)
#pragma unroll
            for (int i = 0; i < 8; i++) {
                int r = 2 * i;
                float p0 = __expf(sv[kt][r] - mnew);
                float p1 = __expf(sv[kt][r + 1] - mnew);
                ps += p0 + p1;
                unsigned pk = (unsigned)bf16rne(p0) | ((unsigned)bf16rne(p1) << 16);
                int key = kt * 32 + (r & 3) + 8 * (r >> 2) + 4 * h;
                *(unsigned*)&sPw[l * 88 + key] = pk;
            }
        ps += __shfl_xor(ps, 32);
        lI = lI * al + ps;
        mI = mnew;

        // rescale accumulators (col q = l matches D-layout col = lane&31)
#pragma unroll
        for (int ct = 0; ct < 4; ct++)
#pragma unroll
            for (int r = 0; r < 16; r++) yacc[ct][r] *= al;

        // PV: y^T += g^T . P  (B-frags from per-wave sP, same-wave visibility)
        bfrag pf[4];
#pragma unroll
        for (int s = 0; s < 4; s++)
            pf[s] = *(const bfrag*)&sPw[l * 88 + s * 16 + h * 8];
#pragma unroll
        for (int ct = 0; ct < 4; ct++)
#pragma unroll
            for (int s = 0; s < 4; s++) {
                bfrag ga = *(const bfrag*)&sG[(ct * 32 + l) * 72 + s * 16 + h * 8];
                yacc[ct] = __builtin_amdgcn_mfma_f32_32x32x16_bf16(ga, pf[s], yacc[ct], 0, 0, 0);
            }
    }

    // epilogue: bf16 unnormalized partials + (m,l)
    short* yb = yp + (((size_t)split * B_ + b) * CI_) * N_;
#pragma unroll
    for (int ct = 0; ct < 4; ct++)
#pragma unroll
        for (int r = 0; r < 16; r++) {
            int c = ct * 32 + (r & 3) + 8 * (r >> 2) + 4 * h;
            yb[(size_t)c * N_ + qg] = (short)bf16rne(yacc[ct][r]);
        }
    if (h == 0) {
        float* mlb = ml + ((split * B_ + b) * 2) * N_;
        mlb[qg] = mI;
        mlb[N_ + qg] = lI;
    }
}

// ---------------- flash merge of the four key-splits ----------------
__global__ __launch_bounds__(256) void merge_kernel(
    const short* __restrict__ yp, const float* __restrict__ ml, float* __restrict__ y)
{
    int idx = blockIdx.x * 256 + threadIdx.x;   // over CI*N/4
    int b = blockIdx.y;
    int e = idx * 4;
    int c = e >> 13;
    int n0 = e & (N_ - 1);

    float4 mv[4], lv[4];
#pragma unroll
    for (int s = 0; s < 4; s++) {
        const float* mlb = ml + ((s * B_ + b) * 2) * N_;
        mv[s] = *(const float4*)&mlb[n0];
        lv[s] = *(const float4*)&mlb[N_ + n0];
    }
    float ms[4] = {-INFINITY, -INFINITY, -INFINITY, -INFINITY};
#pragma unroll
    for (int s = 0; s < 4; s++) {
        ms[0] = fmaxf(ms[0], mv[s].x); ms[1] = fmaxf(ms[1], mv[s].y);
        ms[2] = fmaxf(ms[2], mv[s].z); ms[3] = fmaxf(ms[3], mv[s].w);
    }
    float num[4] = {0.f, 0.f, 0.f, 0.f}, den[4] = {0.f, 0.f, 0.f, 0.f};
#pragma unroll
    for (int s = 0; s < 4; s++) {
        s4v yv4 = *(const s4v*)&yp[(((size_t)s * B_ + b) * CI_ + c) * N_ + n0];
        float es[4];
        es[0] = __expf(mv[s].x - ms[0]); es[1] = __expf(mv[s].y - ms[1]);
        es[2] = __expf(mv[s].z - ms[2]); es[3] = __expf(mv[s].w - ms[3]);
        den[0] += lv[s].x * es[0]; den[1] += lv[s].y * es[1];
        den[2] += lv[s].z * es[2]; den[3] += lv[s].w * es[3];
#pragma unroll
        for (int j = 0; j < 4; j++) {
            float yv = __uint_as_float((unsigned)(unsigned short)yv4[j] << 16);
            num[j] += yv * es[j];
        }
    }
    float4 o;
    o.x = num[0] / den[0]; o.y = num[1] / den[1];
    o.z = num[2] / den[2]; o.w = num[3] / den[3];
    *(float4*)&y[((size_t)b * CI_ + c) * N_ + n0] = o;
}

// ---------------- Wy = W_w @ y + W_b  -> d_out (scratch) ----------------
__global__ __launch_bounds__(256) void wy_kernel(
    const float* __restrict__ y, const float* __restrict__ Ww,
    const float* __restrict__ Wb, float* __restrict__ out)
{
    int n = blockIdx.x * 256 + threadIdx.x;
    int d0 = blockIdx.y * 32;
    int b = blockIdx.z;
    const float* ypb = y + (size_t)b * CI_ * N_ + n;
    float acc[32];
#pragma unroll
    for (int dd = 0; dd < 32; dd++) acc[dd] = 0.f;
#pragma unroll 4
    for (int c = 0; c < CI_; c++) {
        float yv = ypb[(size_t)c * N_];
#pragma unroll
        for (int dd = 0; dd < 32; dd++)
            acc[dd] = fmaf(Ww[(d0 + dd) * CI_ + c], yv, acc[dd]);
    }
    float* op = out + (size_t)b * D_ * N_ + (size_t)d0 * N_ + n;
#pragma unroll
    for (int dd = 0; dd < 32; dd++) op[(size_t)dd * N_] = acc[dd] + Wb[d0 + dd];
}

// ---------------- per-channel batch stats over (b, n) ----------------
__global__ __launch_bounds__(256) void stats_kernel(
    const float* __restrict__ wy, float* __restrict__ mean, float* __restrict__ rstd)
{
    __shared__ float ssum[256], ssq[256];
    int d = blockIdx.x;
    int tid = threadIdx.x;
    float s = 0.f, sq = 0.f;
    for (int b = 0; b < B_; b++) {
        const float* p = wy + (size_t)b * D_ * N_ + (size_t)d * N_;
        for (int i = tid; i < N_; i += 256) {
            float v = p[i];
            s += v;
            sq = fmaf(v, v, sq);
        }
    }
    ssum[tid] = s; ssq[tid] = sq;
    __syncthreads();
    for (int st = 128; st > 0; st >>= 1) {
        if (tid < st) { ssum[tid] += ssum[tid + st]; ssq[tid] += ssq[tid + st]; }
        __syncthreads();
    }
    if (tid == 0) {
        float inv = 1.0f / (float)(B_ * N_);
        float mn = ssum[0] * inv;
        float var = ssq[0] * inv - mn * mn;
        mean[d] = mn;
        rstd[d] = rsqrtf(var + BN_EPS_);
    }
}

// ---------------- BN (affine) + residual, in-place on d_out ----------------
__global__ __launch_bounds__(256) void bn_res_kernel(
    float* __restrict__ out, const float* __restrict__ f,
    const float* __restrict__ mean, const float* __restrict__ rstd,
    const float* __restrict__ gamma, const float* __restrict__ beta)
{
    int i = blockIdx.x * 256 + threadIdx.x;
    size_t e = (size_t)i * 4;
    int d = (int)((e >> 13) & 255);
    float4 wy = ((const float4*)out)[i];
    float4 ff = ((const float4*)f)[i];
    float sc = rstd[d] * gamma[d];
    float mn = mean[d];
    float bt = beta[d];
    float4 r;
    r.x = (wy.x - mn) * sc + bt + ff.x;
    r.y = (wy.y - mn) * sc + bt + ff.y;
    r.z = (wy.z - mn) * sc + bt + ff.z;
    r.w = (wy.w - mn) * sc + bt + ff.w;
    ((float4*)out)[i] = r;
}

extern "C" void kernel_launch(void* const* d_in, const int* in_sizes, int n_in,
                              void* d_out, int out_size, void* d_ws, size_t ws_size,
                              hipStream_t stream)
{
    const float* f   = (const float*)d_in[0];
    const float* g_w = (const float*)d_in[1];
    const float* g_b = (const float*)d_in[2];
    const float* t_w = (const float*)d_in[3];
    const float* t_b = (const float*)d_in[4];
    const float* p_w = (const float*)d_in[5];
    const float* p_b = (const float*)d_in[6];
    const float* W_w = (const float*)d_in[7];
    const float* W_b = (const float*)d_in[8];
    const float* gam = (const float*)d_in[9];
    const float* bet = (const float*)d_in[10];
    float* out = (float*)d_out;
    float* ws = (float*)d_ws;

    short* wall = (short*)(ws + OFF_WALL);
    short* th_t = (short*)(ws + OFF_THT);
    short* ph_t = (short*)(ws + OFF_PHT);
    short* g_t  = (short*)(ws + OFF_GT);
    short* ypart = (short*)(ws + OFF_YP);
    float* mlp = ws + OFF_ML;
    float* yws = ws + OFF_Y;
    float* mnp = ws + OFF_MEAN;
    float* rsp = ws + OFF_RSTD;

    wconv_kernel<<<384, 256, 0, stream>>>(g_w, t_w, p_w, wall);
    proj_kernel<<<dim3(N_ / 32, B_), 256, 0, stream>>>(f, wall, t_b, g_b, p_b,
                                                       th_t, g_t, ph_t);
    attn_kernel<<<dim3(N_ / 128, B_, 4), 256, 0, stream>>>(th_t, ph_t, g_t, ypart, mlp);
    merge_kernel<<<dim3(CI_ * N_ / 4 / 256, B_), 256, 0, stream>>>(ypart, mlp, yws);
    wy_kernel<<<dim3(N_ / 256, D_ / 32, B_), 256, 0, stream>>>(yws, W_w, W_b, out);
    stats_kernel<<<D_, 256, 0, stream>>>(out, mnp, rsp);
    bn_res_kernel<<<(B_ * D_ * N_ / 4) / 256, 256, 0, stream>>>(out, f, mnp, rsp, gam, bet);
}